// Round 2
// baseline (475.868 us; speedup 1.0000x reference)
//
#include <hip/hip_runtime.h>

#define NROWS (16*16384)   // 262144
#define NJ 256
#define OUT_LOSS 16777216
#define OUT_PERP 16777217
#define OUT_IDX  16777218

typedef float f32x4  __attribute__((ext_vector_type(4)));
typedef float f32x16 __attribute__((ext_vector_type(16)));
typedef short s16x8  __attribute__((ext_vector_type(8)));

__device__ inline unsigned short f2bf(float f){
  unsigned u = __builtin_bit_cast(unsigned, f);
  unsigned r = (u + 0x7FFFu + ((u >> 16) & 1u)) >> 16;
  return (unsigned short)r;
}
__device__ inline float bf2f(unsigned short h){
  unsigned u = ((unsigned)h) << 16;
  return __builtin_bit_cast(float, u);
}

// ws layout: [0,8) fp64 loss | [8,12) qcnt | [16,1040) wsCnt[256] | [1040,..) qrows

__global__ __launch_bounds__(256, 2) void vq_main(
    const float* __restrict__ z, const float* __restrict__ oh,
    const float* __restrict__ W, float* __restrict__ out,
    double* __restrict__ wsLoss, unsigned* __restrict__ wsCnt,
    unsigned* __restrict__ qcnt, unsigned* __restrict__ qrows, unsigned qcap)
{
  __shared__ short e1l[NJ*64];
  __shared__ short e2l[NJ*64];
  __shared__ float enl[NJ];
  __shared__ unsigned hist[NJ];

  float mv = oh[0]; int pos = 0;
  #pragma unroll
  for (int i = 1; i < 7; i++){ float v = oh[i]; if (v > mv){ mv = v; pos = i; } }

  const int tid = threadIdx.x;

  // stage codebook split into bf16 hi/lo, slot-swizzled
  {
    const int j = tid;
    const float* Wr = W + (size_t)(pos*NJ + j)*64;
    double en = 0.0;
    #pragma unroll
    for (int s = 0; s < 8; s++){
      f32x4 a = *(const f32x4*)(Wr + s*8);
      f32x4 b = *(const f32x4*)(Wr + s*8 + 4);
      s16x8 p1, p2;
      #pragma unroll
      for (int i = 0; i < 8; i++){
        float vv = (i < 4) ? a[i] : b[i-4];
        unsigned short x1 = f2bf(vv);
        float rr = vv - bf2f(x1);
        p1[i] = (short)x1;
        p2[i] = (short)f2bf(rr);
        en += (double)vv * (double)vv;
      }
      const int slot = s ^ (j & 7);
      *(s16x8*)(e1l + j*64 + slot*8) = p1;
      *(s16x8*)(e2l + j*64 + slot*8) = p2;
    }
    enl[j] = (float)en;
    hist[j] = 0u;
  }
  __syncthreads();

  const int w   = tid >> 6;
  const int l   = tid & 63;
  const int l31 = l & 31;
  const int lh  = l >> 5;

  const int rblk = (int)blockIdx.x * 128;
  const int r    = rblk + w*32 + l31;
  const int b_i  = r >> 14;
  const int t    = r & 16383;
  const float* zr = z + (size_t)r * 64;

  // split-precision MFMA: acc = dot(e_j, z_r)
  f32x16 acc[8] = {};
  #pragma unroll
  for (int ks = 0; ks < 4; ks++){
    const int k0 = ks*16 + lh*8;
    f32x4 za = *(const f32x4*)(zr + k0);
    f32x4 zb = *(const f32x4*)(zr + k0 + 4);
    s16x8 z1f, z2f;
    #pragma unroll
    for (int i = 0; i < 8; i++){
      float vv = (i < 4) ? za[i] : zb[i-4];
      unsigned short x1 = f2bf(vv);
      float rr = vv - bf2f(x1);
      z1f[i] = (short)x1;
      z2f[i] = (short)f2bf(rr);
    }
    #pragma unroll
    for (int jt = 0; jt < 8; jt++){
      const int jrow = jt*32 + l31;
      const int slot = (ks*2 + lh) ^ (jrow & 7);
      const s16x8 e1f = *(const s16x8*)(e1l + jrow*64 + slot*8);
      const s16x8 e2f = *(const s16x8*)(e2l + jrow*64 + slot*8);
      acc[jt] = __builtin_amdgcn_mfma_f32_32x32x16_bf16(e1f, z1f, acc[jt], 0, 0, 0);
      acc[jt] = __builtin_amdgcn_mfma_f32_32x32x16_bf16(e1f, z2f, acc[jt], 0, 0, 0);
      acc[jt] = __builtin_amdgcn_mfma_f32_32x32x16_bf16(e2f, z1f, acc[jt], 0, 0, 0);
    }
  }

  // lane-local (min, runner-up, argmin) over s_j = ||e_j||^2 - 2 dot_j
  float m1 = 3.4e38f, m2 = 3.4e38f; int j1 = 0;
  #pragma unroll
  for (int jt = 0; jt < 8; jt++){
    #pragma unroll
    for (int rq = 0; rq < 4; rq++){
      f32x4 en4 = *(const f32x4*)(enl + jt*32 + rq*8 + lh*4);
      #pragma unroll
      for (int q = 0; q < 4; q++){
        const int reg = rq*4 + q;
        float s  = fmaf(-2.0f, acc[jt][reg], en4[q]);
        int   jj = jt*32 + q + 8*rq + 4*lh;
        bool  lt = s < m1;
        m2 = fminf(m2, lt ? m1 : s);
        j1 = lt ? jj : j1;
        m1 = fminf(m1, s);
      }
    }
  }
  {
    float om1 = __shfl_xor(m1, 32);
    float om2 = __shfl_xor(m2, 32);
    int   oj1 = __shfl_xor(j1, 32);
    float nm2 = fminf(fminf(m2, om2), fmaxf(m1, om1));
    if (om1 < m1){ m1 = om1; j1 = oj1; }
    m2 = nm2;
  }

  // near-tie (fp32-reference-quantization zone): enqueue for np-exact replay.
  // bound: ref quantization distorts pair gaps by <= 2*ulp(zz) <= 6.1e-5 (zz<256)
  int resc = (m2 - m1 <= 6.4e-5f) ? 1 : 0;
  if (resc && lh == 0){
    unsigned slot = atomicAdd(qcnt, 1u);
    if (slot < qcap){ qrows[slot] = (unsigned)r; }
    else {
      // ws-overflow safety net: fp64-exact argmin inline (degraded tie semantics)
      double best = 1e300; int bj = 0;
      for (int j = 0; j < NJ; j++){
        const float* er = W + (size_t)(pos*NJ + j)*64;
        double en = 0.0, dt = 0.0;
        for (int k = 0; k < 64; k++){
          double e = (double)er[k];
          en += e*e;
          dt = fma(e, (double)zr[k], dt);
        }
        double sj = en - 2.0*dt;
        if (sj < best){ best = sj; bj = j; }
      }
      j1 = bj; resc = 0;
    }
  }
  j1   = __shfl(j1, l31);
  resc = __shfl(resc, l31);

  double lsum = 0.0;
  if (!resc){
    if (lh == 0){
      out[(size_t)OUT_IDX + r] = (float)j1;
      atomicAdd(&hist[j1], 1u);
    }
    const float* Er = W + (size_t)(pos*NJ + j1)*64;
    float* zq = out + (size_t)b_i * 1048576 + t;
    #pragma unroll
    for (int ks = 0; ks < 4; ks++){
      const int d0 = ks*16 + lh*8;
      f32x4 ea = *(const f32x4*)(Er + d0);
      f32x4 eb = *(const f32x4*)(Er + d0 + 4);
      f32x4 za = *(const f32x4*)(zr + d0);
      f32x4 zb = *(const f32x4*)(zr + d0 + 4);
      #pragma unroll
      for (int i = 0; i < 8; i++){
        float e  = (i < 4) ? ea[i] : eb[i-4];
        float zz = (i < 4) ? za[i] : zb[i-4];
        float df = e - zz;
        lsum = fma((double)df, (double)df, lsum);
        zq[(size_t)(d0 + i) * 16384] = zz + df;
      }
    }
  }
  #pragma unroll
  for (int off = 1; off < 64; off <<= 1) lsum += __shfl_xor(lsum, off);
  if (l == 0 && lsum != 0.0) atomicAdd(wsLoss, lsum);

  __syncthreads();
  { unsigned c = hist[tid]; if (c) atomicAdd(wsCnt + tid, c); }
}

// numpy-fp32 bit-exact replay for queued rows. One wave per row.
__global__ __launch_bounds__(256, 2) void vq_rescue(
    const float* __restrict__ z, const float* __restrict__ oh,
    const float* __restrict__ W, float* __restrict__ out,
    double* __restrict__ wsLoss, unsigned* __restrict__ wsCnt,
    const unsigned* __restrict__ qcnt, const unsigned* __restrict__ qrows,
    unsigned qcap)
{
  #pragma clang fp contract(off)
  __shared__ float elds[NJ*64];   // 64 KB, element-XOR swizzled

  float mvv = oh[0]; int pos = 0;
  #pragma unroll
  for (int i = 1; i < 7; i++){ float v = oh[i]; if (v > mvv){ mvv = v; pos = i; } }
  const float* E = W + (size_t)pos * (NJ*64);

  const int tid = threadIdx.x;
  {
    const float* er = E + (size_t)tid * 64;
    #pragma unroll 16
    for (int k = 0; k < 64; k++)
      elds[tid*64 + (k ^ (tid & 31))] = er[k];
  }
  __syncthreads();

  const int wv = tid >> 6, l = tid & 63;
  const int x  = l & 31;
  const unsigned nq = min(*qcnt, qcap);
  const unsigned wgid = blockIdx.x*4u + (unsigned)wv;
  const unsigned nw   = gridDim.x*4u;

  for (unsigned i = wgid; i < nq; i += nw){
    const int r = __builtin_amdgcn_readfirstlane((int)qrows[i]);
    const float* zr = z + (size_t)r * 64;

    float zk[64];
    #pragma unroll
    for (int k = 0; k < 64; k++) zk[k] = zr[k];   // uniform -> scalar loads

    // numpy pairwise (8-accumulator) sum of fl(zk^2)
    float r8[8];
    #pragma unroll
    for (int k = 0; k < 8; k++){ float p = zk[k]*zk[k]; r8[k] = p; }
    #pragma unroll
    for (int k = 8; k < 64; k++){ float p = zk[k]*zk[k]; r8[k & 7] += p; }
    const float zzs = ((r8[0]+r8[1])+(r8[2]+r8[3]))+((r8[4]+r8[5])+(r8[6]+r8[7]));

    float dbest = 3.4e38f; int jbest = 0;
    #pragma unroll
    for (int q = 0; q < 4; q++){
      const int j = l + 64*q;
      float dot = 0.0f;
      float s8[8];
      #pragma unroll
      for (int k = 0; k < 8; k++){
        float ev = elds[j*64 + (k ^ x)];
        dot = fmaf(ev, zk[k], dot);
        s8[k] = ev*ev;
      }
      #pragma unroll
      for (int k = 8; k < 64; k++){
        float ev = elds[j*64 + (k ^ x)];
        dot = fmaf(ev, zk[k], dot);
        s8[k & 7] += ev*ev;
      }
      float ee = ((s8[0]+s8[1])+(s8[2]+s8[3]))+((s8[4]+s8[5])+(s8[6]+s8[7]));
      float A  = zzs + ee;          // fp32, quantizes at ulp(zz)
      float tw = 2.0f*dot;          // exact
      float d  = A - tw;            // fp32
      if (d < dbest){ dbest = d; jbest = j; }   // per-lane j ascending
    }
    #pragma unroll
    for (int off = 32; off > 0; off >>= 1){
      float od = __shfl_xor(dbest, off);
      int   oj = __shfl_xor(jbest, off);
      if (od < dbest || (od == dbest && oj < jbest)){ dbest = od; jbest = oj; }
    }

    // epilogue for this row
    const int b_i = r >> 14;
    const int t   = r & 16383;
    const float* eb = E + (size_t)jbest * 64;
    float ze = zr[l];
    float ev = eb[l];
    float df = ev - ze;
    out[(size_t)b_i * 1048576 + (size_t)l * 16384 + t] = ze + df;
    double ls = (double)df * (double)df;
    #pragma unroll
    for (int off = 1; off < 64; off <<= 1) ls += __shfl_xor(ls, off);
    if (l == 0){
      atomicAdd(wsLoss, ls);
      out[(size_t)OUT_IDX + r] = (float)jbest;
      atomicAdd(wsCnt + jbest, 1u);
    }
  }
}

__global__ void vq_fin(const double* __restrict__ wsLoss,
                       const unsigned* __restrict__ wsCnt,
                       float* __restrict__ out)
{
  __shared__ double sh[256];
  const int t = threadIdx.x;
  double c  = (double)wsCnt[t];
  double em = c / (double)NROWS;
  sh[t] = em * log(em + 1e-10);
  __syncthreads();
  for (int s = 128; s > 0; s >>= 1){
    if (t < s) sh[t] += sh[t + s];
    __syncthreads();
  }
  if (t == 0){
    out[OUT_LOSS] = (float)(1.25 * (wsLoss[0] / 16777216.0));
    out[OUT_PERP] = (float)exp(-sh[0]);
  }
}

extern "C" void kernel_launch(void* const* d_in, const int* in_sizes, int n_in,
                              void* d_out, int out_size, void* d_ws, size_t ws_size,
                              hipStream_t stream)
{
  const float* z  = (const float*)d_in[0];
  const float* oh = (const float*)d_in[1];
  const float* W  = (const float*)d_in[2];
  float* out = (float*)d_out;
  double*   wsLoss = (double*)d_ws;
  unsigned* qcnt   = (unsigned*)((char*)d_ws + 8);
  unsigned* wsCnt  = (unsigned*)((char*)d_ws + 16);
  unsigned* qrows  = (unsigned*)((char*)d_ws + 1040);
  unsigned  qcap   = (ws_size > 1040) ? (unsigned)((ws_size - 1040) / 4) : 0u;
  if (qcap > (unsigned)NROWS) qcap = (unsigned)NROWS;

  hipMemsetAsync(d_ws, 0, 1040, stream);
  vq_main<<<dim3(2048), dim3(256), 0, stream>>>(z, oh, W, out, wsLoss, wsCnt,
                                                qcnt, qrows, qcap);
  vq_rescue<<<dim3(512), dim3(256), 0, stream>>>(z, oh, W, out, wsLoss, wsCnt,
                                                 qcnt, qrows, qcap);
  vq_fin<<<dim3(1), dim3(256), 0, stream>>>(wsLoss, wsCnt, out);
}

// Round 3
// 347.399 us; speedup vs baseline: 1.3698x; 1.3698x over previous
//
#include <hip/hip_runtime.h>

#define NROWS (16*16384)   // 262144
#define NJ 256
#define NBLK 1024          // main blocks, 256 rows each
#define OUT_LOSS 16777216
#define OUT_PERP 16777217
#define OUT_IDX  16777218

typedef float f32x4  __attribute__((ext_vector_type(4)));
typedef float f32x16 __attribute__((ext_vector_type(16)));
typedef short s16x8  __attribute__((ext_vector_type(8)));

__device__ inline unsigned short f2bf(float f){
  unsigned u = __builtin_bit_cast(unsigned, f);
  unsigned r = (u + 0x7FFFu + ((u >> 16) & 1u)) >> 16;
  return (unsigned short)r;
}
__device__ inline float bf2f(unsigned short h){
  unsigned u = ((unsigned)h) << 16;
  return __builtin_bit_cast(float, u);
}

// ws layout:
//   [0,4)      qcnt
//   [64,1088)  wsCnt[256]      (rescue count atomics; memset 0)
//   [1088,9280)    lossA[1024] (per main block, plain store)
//   [9280,25664)   lossB[2048] (per rescue wave, plain store)
//   [25664, +4*qcap)  qrows
//   [align256, +1MB)  cntA[1024][256] (per main block, plain store) -- optional

__global__ __launch_bounds__(512, 2) void vq_main(
    const float* __restrict__ z, const float* __restrict__ oh,
    const float* __restrict__ W, float* __restrict__ out,
    double* __restrict__ lossA, unsigned* __restrict__ cntA,
    unsigned* __restrict__ wsCnt,
    unsigned* __restrict__ qcnt, unsigned* __restrict__ qrows, unsigned qcap)
{
  __shared__ short e1l[NJ*64];
  __shared__ short e2l[NJ*64];
  __shared__ float enl[NJ];
  __shared__ unsigned hist[NJ];
  __shared__ double sLoss[8];

  float mv = oh[0]; int pos = 0;
  #pragma unroll
  for (int i = 1; i < 7; i++){ float v = oh[i]; if (v > mv){ mv = v; pos = i; } }

  const int tid = threadIdx.x;          // 0..511

  // stage codebook: 2 threads per row j (half-row each), bf16 hi/lo split
  {
    const int j = tid >> 1, half = tid & 1;
    const float* Wr = W + (size_t)(pos*NJ + j)*64;
    double en = 0.0;
    #pragma unroll
    for (int s4 = 0; s4 < 4; s4++){
      const int s = half*4 + s4;
      f32x4 a = *(const f32x4*)(Wr + s*8);
      f32x4 b = *(const f32x4*)(Wr + s*8 + 4);
      s16x8 p1, p2;
      #pragma unroll
      for (int i = 0; i < 8; i++){
        float vv = (i < 4) ? a[i] : b[i-4];
        unsigned short x1 = f2bf(vv);
        float rr = vv - bf2f(x1);
        p1[i] = (short)x1;
        p2[i] = (short)f2bf(rr);
        en += (double)vv * (double)vv;
      }
      const int slot = s ^ (j & 7);     // XOR swizzle
      *(s16x8*)(e1l + j*64 + slot*8) = p1;
      *(s16x8*)(e2l + j*64 + slot*8) = p2;
    }
    en += __shfl_xor(en, 1);
    if (half == 0) enl[j] = (float)en;
    if (tid < NJ) hist[tid] = 0u;
  }
  __syncthreads();

  const int w   = tid >> 6;             // 0..7
  const int l   = tid & 63;
  const int l31 = l & 31;
  const int lh  = l >> 5;

  const int r    = (int)blockIdx.x * 256 + w*32 + l31;
  const int b_i  = r >> 14;
  const int t    = r & 16383;
  const float* zr = z + (size_t)r * 64;

  // split-precision MFMA: acc = dot(e_j, z_r)
  f32x16 acc[8] = {};
  #pragma unroll
  for (int ks = 0; ks < 4; ks++){
    const int k0 = ks*16 + lh*8;
    f32x4 za = *(const f32x4*)(zr + k0);
    f32x4 zb = *(const f32x4*)(zr + k0 + 4);
    s16x8 z1f, z2f;
    #pragma unroll
    for (int i = 0; i < 8; i++){
      float vv = (i < 4) ? za[i] : zb[i-4];
      unsigned short x1 = f2bf(vv);
      float rr = vv - bf2f(x1);
      z1f[i] = (short)x1;
      z2f[i] = (short)f2bf(rr);
    }
    #pragma unroll
    for (int jt = 0; jt < 8; jt++){
      const int jrow = jt*32 + l31;
      const int slot = (ks*2 + lh) ^ (jrow & 7);
      const s16x8 e1f = *(const s16x8*)(e1l + jrow*64 + slot*8);
      const s16x8 e2f = *(const s16x8*)(e2l + jrow*64 + slot*8);
      acc[jt] = __builtin_amdgcn_mfma_f32_32x32x16_bf16(e1f, z1f, acc[jt], 0, 0, 0);
      acc[jt] = __builtin_amdgcn_mfma_f32_32x32x16_bf16(e1f, z2f, acc[jt], 0, 0, 0);
      acc[jt] = __builtin_amdgcn_mfma_f32_32x32x16_bf16(e2f, z1f, acc[jt], 0, 0, 0);
    }
  }

  // lane-local (min, runner-up, argmin) over s_j = ||e_j||^2 - 2 dot_j
  float m1 = 3.4e38f, m2 = 3.4e38f; int j1 = 0;
  #pragma unroll
  for (int jt = 0; jt < 8; jt++){
    #pragma unroll
    for (int rq = 0; rq < 4; rq++){
      f32x4 en4 = *(const f32x4*)(enl + jt*32 + rq*8 + lh*4);
      #pragma unroll
      for (int q = 0; q < 4; q++){
        const int reg = rq*4 + q;
        float s  = fmaf(-2.0f, acc[jt][reg], en4[q]);
        int   jj = jt*32 + q + 8*rq + 4*lh;
        bool  lt = s < m1;
        m2 = fminf(m2, lt ? m1 : s);
        j1 = lt ? jj : j1;
        m1 = fminf(m1, s);
      }
    }
  }
  {
    float om1 = __shfl_xor(m1, 32);
    float om2 = __shfl_xor(m2, 32);
    int   oj1 = __shfl_xor(j1, 32);
    float nm2 = fminf(fminf(m2, om2), fmaxf(m1, om1));
    if (om1 < m1){ m1 = om1; j1 = oj1; }
    m2 = nm2;
  }

  // near-tie rows: enqueue for numpy-fp32 exact replay (gap bound 2*ulp(64)*2)
  int resc = (m2 - m1 <= 6.4e-5f) ? 1 : 0;
  if (resc && lh == 0){
    unsigned slot = atomicAdd(qcnt, 1u);
    if (slot < qcap){ qrows[slot] = (unsigned)r; }
    else {
      double best = 1e300; int bj = 0;
      for (int j = 0; j < NJ; j++){
        const float* er = W + (size_t)(pos*NJ + j)*64;
        double en = 0.0, dt = 0.0;
        for (int k = 0; k < 64; k++){
          double e = (double)er[k];
          en += e*e;
          dt = fma(e, (double)zr[k], dt);
        }
        double sj = en - 2.0*dt;
        if (sj < best){ best = sj; bj = j; }
      }
      j1 = bj; resc = 0;
    }
  }
  j1   = __shfl(j1, l31);
  resc = __shfl(resc, l31);

  double lsum = 0.0;
  if (!resc){
    if (lh == 0){
      out[(size_t)OUT_IDX + r] = (float)j1;
      atomicAdd(&hist[j1], 1u);
    }
    const float* Er = W + (size_t)(pos*NJ + j1)*64;
    float* zq = out + (size_t)b_i * 1048576 + t;
    #pragma unroll
    for (int ks = 0; ks < 4; ks++){
      const int d0 = ks*16 + lh*8;
      f32x4 ea = *(const f32x4*)(Er + d0);
      f32x4 eb = *(const f32x4*)(Er + d0 + 4);
      f32x4 za = *(const f32x4*)(zr + d0);
      f32x4 zb = *(const f32x4*)(zr + d0 + 4);
      #pragma unroll
      for (int i = 0; i < 8; i++){
        float e  = (i < 4) ? ea[i] : eb[i-4];
        float zz = (i < 4) ? za[i] : zb[i-4];
        float df = e - zz;
        lsum = fma((double)df, (double)df, lsum);
        zq[(size_t)(d0 + i) * 16384] = zz + df;
      }
    }
  }
  #pragma unroll
  for (int off = 1; off < 64; off <<= 1) lsum += __shfl_xor(lsum, off);
  if (l == 0) sLoss[w] = lsum;
  __syncthreads();

  if (tid == 0){
    double bs = 0.0;
    #pragma unroll
    for (int i = 0; i < 8; i++) bs += sLoss[i];
    lossA[blockIdx.x] = bs;
  }
  if (tid < NJ){
    unsigned c = hist[tid];
    if (cntA) cntA[(size_t)blockIdx.x * NJ + tid] = c;
    else if (c) atomicAdd(wsCnt + tid, c);
  }
}

// numpy-fp32 bit-exact replay for queued rows. One wave per row-iteration.
__global__ __launch_bounds__(256, 2) void vq_rescue(
    const float* __restrict__ z, const float* __restrict__ oh,
    const float* __restrict__ W, float* __restrict__ out,
    double* __restrict__ lossB, unsigned* __restrict__ wsCnt,
    const unsigned* __restrict__ qcnt, const unsigned* __restrict__ qrows,
    unsigned qcap)
{
  #pragma clang fp contract(off)
  __shared__ float elds[NJ*64];   // 64 KB, element-XOR swizzled

  float mvv = oh[0]; int pos = 0;
  #pragma unroll
  for (int i = 1; i < 7; i++){ float v = oh[i]; if (v > mvv){ mvv = v; pos = i; } }
  const float* E = W + (size_t)pos * (NJ*64);

  const int tid = threadIdx.x;
  {
    const float* er = E + (size_t)tid * 64;
    #pragma unroll 16
    for (int k = 0; k < 64; k++)
      elds[tid*64 + (k ^ (tid & 31))] = er[k];
  }
  __syncthreads();

  const int wv = tid >> 6, l = tid & 63;
  const int x  = l & 31;
  const unsigned nq = min(*qcnt, qcap);
  const unsigned wgid = blockIdx.x*4u + (unsigned)wv;
  const unsigned nw   = gridDim.x*4u;

  double rloss = 0.0;

  for (unsigned i = wgid; i < nq; i += nw){
    const int r = __builtin_amdgcn_readfirstlane((int)qrows[i]);
    const float* zr = z + (size_t)r * 64;

    float zk[64];
    #pragma unroll
    for (int k = 0; k < 64; k++) zk[k] = zr[k];

    // numpy pairwise (8-accumulator) sum of fl(zk^2)
    float r8[8];
    #pragma unroll
    for (int k = 0; k < 8; k++){ float p = zk[k]*zk[k]; r8[k] = p; }
    #pragma unroll
    for (int k = 8; k < 64; k++){ float p = zk[k]*zk[k]; r8[k & 7] += p; }
    const float zzs = ((r8[0]+r8[1])+(r8[2]+r8[3]))+((r8[4]+r8[5])+(r8[6]+r8[7]));

    float dbest = 3.4e38f; int jbest = 0;
    #pragma unroll
    for (int q = 0; q < 4; q++){
      const int j = l + 64*q;
      float dot = 0.0f;
      float s8[8];
      #pragma unroll
      for (int k = 0; k < 8; k++){
        float ev = elds[j*64 + (k ^ x)];
        dot = fmaf(ev, zk[k], dot);
        s8[k] = ev*ev;
      }
      #pragma unroll
      for (int k = 8; k < 64; k++){
        float ev = elds[j*64 + (k ^ x)];
        dot = fmaf(ev, zk[k], dot);
        s8[k & 7] += ev*ev;
      }
      float ee = ((s8[0]+s8[1])+(s8[2]+s8[3]))+((s8[4]+s8[5])+(s8[6]+s8[7]));
      float A  = zzs + ee;
      float tw = 2.0f*dot;
      float d  = A - tw;
      if (d < dbest){ dbest = d; jbest = j; }
    }
    #pragma unroll
    for (int off = 32; off > 0; off >>= 1){
      float od = __shfl_xor(dbest, off);
      int   oj = __shfl_xor(jbest, off);
      if (od < dbest || (od == dbest && oj < jbest)){ dbest = od; jbest = oj; }
    }

    const int b_i = r >> 14;
    const int t   = r & 16383;
    const float* eb = E + (size_t)jbest * 64;
    float ze = zr[l];
    float ev = eb[l];
    float df = ev - ze;
    out[(size_t)b_i * 1048576 + (size_t)l * 16384 + t] = ze + df;
    double ls = (double)df * (double)df;
    #pragma unroll
    for (int off = 1; off < 64; off <<= 1) ls += __shfl_xor(ls, off);
    rloss += ls;
    if (l == 0){
      out[(size_t)OUT_IDX + r] = (float)jbest;
      atomicAdd(wsCnt + jbest, 1u);   // sparse: ~8K over 256 addrs
    }
  }
  if (l == 0) lossB[wgid] = rloss;    // every wave writes (ws is poisoned)
}

__global__ __launch_bounds__(1024) void vq_fin(
    const double* __restrict__ lossA, const double* __restrict__ lossB,
    const unsigned* __restrict__ cntA, const unsigned* __restrict__ wsCnt,
    float* __restrict__ out)
{
  __shared__ double sh[1024];
  __shared__ unsigned sc[1024];
  __shared__ double sent[NJ];
  const int t = threadIdx.x;

  sh[t] = lossA[t] + lossB[t] + lossB[1024 + t];

  const int j = t & 255, part = t >> 8;          // 4 parts x 256 blocks
  unsigned c = 0;
  if (cntA){
    const unsigned* p = cntA + (size_t)part * 256 * NJ + j;
    #pragma unroll 8
    for (int b = 0; b < 256; b++) c += p[(size_t)b * NJ];
  }
  sc[t] = c;
  __syncthreads();

  for (int st = 512; st > 0; st >>= 1){
    if (t < st) sh[t] += sh[t + st];
    __syncthreads();
  }
  if (t < NJ){
    unsigned ct = sc[t] + sc[256+t] + sc[512+t] + sc[768+t] + wsCnt[t];
    double em = (double)ct / (double)NROWS;
    sent[t] = em * log(em + 1e-10);
  }
  __syncthreads();
  for (int st = 128; st > 0; st >>= 1){
    if (t < st) sent[t] += sent[t + st];
    __syncthreads();
  }
  if (t == 0){
    out[OUT_LOSS] = (float)(1.25 * (sh[0] / 16777216.0));
    out[OUT_PERP] = (float)exp(-sent[0]);
  }
}

extern "C" void kernel_launch(void* const* d_in, const int* in_sizes, int n_in,
                              void* d_out, int out_size, void* d_ws, size_t ws_size,
                              hipStream_t stream)
{
  const float* z  = (const float*)d_in[0];
  const float* oh = (const float*)d_in[1];
  const float* W  = (const float*)d_in[2];
  float* out = (float*)d_out;

  char* ws = (char*)d_ws;
  unsigned* qcnt  = (unsigned*)(ws + 0);
  unsigned* wsCnt = (unsigned*)(ws + 64);
  double*   lossA = (double*)(ws + 1088);     // 1024 doubles
  double*   lossB = (double*)(ws + 9280);     // 2048 doubles
  const size_t qoff = 25664;
  unsigned* qrows = (unsigned*)(ws + qoff);

  unsigned qcap = 0;
  unsigned* cntA = nullptr;
  const size_t cntBytes = (size_t)NBLK * NJ * 4;
  if (ws_size >= qoff + 65536*4 + cntBytes + 256){
    qcap = 65536;
    size_t coff = (qoff + 65536*4 + 255) & ~(size_t)255;
    cntA = (unsigned*)(ws + coff);
  } else if (ws_size > qoff + 4){
    qcap = (unsigned)((ws_size - qoff) / 4);
    if (qcap > 65536) qcap = 65536;
  }

  hipMemsetAsync(d_ws, 0, 1088, stream);
  vq_main<<<dim3(NBLK), dim3(512), 0, stream>>>(z, oh, W, out, lossA, cntA,
                                                wsCnt, qcnt, qrows, qcap);
  vq_rescue<<<dim3(512), dim3(256), 0, stream>>>(z, oh, W, out, lossB, wsCnt,
                                                 qcnt, qrows, qcap);
  vq_fin<<<dim3(1), dim3(1024), 0, stream>>>(lossA, lossB, cntA, wsCnt, out);
}

// Round 4
// 204.552 us; speedup vs baseline: 2.3264x; 1.6983x over previous
//
#include <hip/hip_runtime.h>

#define NROWS (16*16384)   // 262144
#define NJ 256
#define NBLK 1024          // main blocks, 256 rows each
#define OUT_LOSS 16777216
#define OUT_PERP 16777217
#define OUT_IDX  16777218

typedef float f32x4  __attribute__((ext_vector_type(4)));
typedef float f32x16 __attribute__((ext_vector_type(16)));
typedef short s16x8  __attribute__((ext_vector_type(8)));

__device__ inline unsigned short f2bf(float f){
  unsigned u = __builtin_bit_cast(unsigned, f);
  unsigned r = (u + 0x7FFFu + ((u >> 16) & 1u)) >> 16;
  return (unsigned short)r;
}
__device__ inline float bf2f(unsigned short h){
  unsigned u = ((unsigned)h) << 16;
  return __builtin_bit_cast(float, u);
}

// ws layout:
//   [0,4096)       wsCnt4[4][256] int   (histogram, 4 replicas; memset 0)
//   [4096,8192)    qn[1024]             (per-block rescue count, plain store)
//   [8192,16384)   lossA[1024] f64      (per main block, plain store)
//   [16384,32768)  lossB[2048] f64      (per rescue wave, plain store)
//   [32768,+1MB)   qrows[1024][segcap]  (r | j1<<18)

__global__ __launch_bounds__(512, 2) void vq_main(
    const float* __restrict__ z, const float* __restrict__ oh,
    const float* __restrict__ W, float* __restrict__ out,
    double* __restrict__ lossA, int* __restrict__ wsCnt4,
    unsigned* __restrict__ qn, unsigned* __restrict__ qrows, unsigned segcap)
{
  __shared__ short e1l[NJ*64];
  __shared__ short e2l[NJ*64];
  __shared__ float enl[NJ];
  __shared__ unsigned hist[NJ];
  __shared__ double sLoss[8];
  __shared__ unsigned qn_lds;

  float mv = oh[0]; int pos = 0;
  #pragma unroll
  for (int i = 1; i < 7; i++){ float v = oh[i]; if (v > mv){ mv = v; pos = i; } }

  const int tid = threadIdx.x;          // 0..511

  // stage codebook: 2 threads per row j, bf16 hi/lo split, XOR slot swizzle
  {
    const int j = tid >> 1, half = tid & 1;
    const float* Wr = W + (size_t)(pos*NJ + j)*64;
    double en = 0.0;
    #pragma unroll
    for (int s4 = 0; s4 < 4; s4++){
      const int s = half*4 + s4;
      f32x4 a = *(const f32x4*)(Wr + s*8);
      f32x4 b = *(const f32x4*)(Wr + s*8 + 4);
      s16x8 p1, p2;
      #pragma unroll
      for (int i = 0; i < 8; i++){
        float vv = (i < 4) ? a[i] : b[i-4];
        unsigned short x1 = f2bf(vv);
        float rr = vv - bf2f(x1);
        p1[i] = (short)x1;
        p2[i] = (short)f2bf(rr);
        en += (double)vv * (double)vv;
      }
      const int slot = s ^ (j & 7);
      *(s16x8*)(e1l + j*64 + slot*8) = p1;
      *(s16x8*)(e2l + j*64 + slot*8) = p2;
    }
    en += __shfl_xor(en, 1);
    if (half == 0) enl[j] = (float)en;
    if (tid < NJ) hist[tid] = 0u;
    if (tid == 0) qn_lds = 0u;
  }
  __syncthreads();

  const int w   = tid >> 6;
  const int l   = tid & 63;
  const int l31 = l & 31;
  const int lh  = l >> 5;

  const int r    = (int)blockIdx.x * 256 + w*32 + l31;
  const int b_i  = r >> 14;
  const int t    = r & 16383;
  const float* zr = z + (size_t)r * 64;

  // split-precision MFMA: acc = dot(e_j, z_r); also accumulate ||z||^2 approx
  f32x16 acc[8] = {};
  float zzp = 0.0f;
  #pragma unroll
  for (int ks = 0; ks < 4; ks++){
    const int k0 = ks*16 + lh*8;
    f32x4 za = *(const f32x4*)(zr + k0);
    f32x4 zb = *(const f32x4*)(zr + k0 + 4);
    s16x8 z1f, z2f;
    #pragma unroll
    for (int i = 0; i < 8; i++){
      float vv = (i < 4) ? za[i] : zb[i-4];
      zzp = fmaf(vv, vv, zzp);
      unsigned short x1 = f2bf(vv);
      float rr = vv - bf2f(x1);
      z1f[i] = (short)x1;
      z2f[i] = (short)f2bf(rr);
    }
    #pragma unroll
    for (int jt = 0; jt < 8; jt++){
      const int jrow = jt*32 + l31;
      const int slot = (ks*2 + lh) ^ (jrow & 7);
      const s16x8 e1f = *(const s16x8*)(e1l + jrow*64 + slot*8);
      const s16x8 e2f = *(const s16x8*)(e2l + jrow*64 + slot*8);
      acc[jt] = __builtin_amdgcn_mfma_f32_32x32x16_bf16(e1f, z1f, acc[jt], 0, 0, 0);
      acc[jt] = __builtin_amdgcn_mfma_f32_32x32x16_bf16(e1f, z2f, acc[jt], 0, 0, 0);
      acc[jt] = __builtin_amdgcn_mfma_f32_32x32x16_bf16(e2f, z1f, acc[jt], 0, 0, 0);
    }
  }
  const float zz = zzp + __shfl_xor(zzp, 32);

  // lane-local (min, runner-up, argmin) over s_j = ||e_j||^2 - 2 dot_j
  float m1 = 3.4e38f, m2 = 3.4e38f; int j1 = 0;
  #pragma unroll
  for (int jt = 0; jt < 8; jt++){
    #pragma unroll
    for (int rq = 0; rq < 4; rq++){
      f32x4 en4 = *(const f32x4*)(enl + jt*32 + rq*8 + lh*4);
      #pragma unroll
      for (int q = 0; q < 4; q++){
        const int reg = rq*4 + q;
        float s  = fmaf(-2.0f, acc[jt][reg], en4[q]);
        int   jj = jt*32 + q + 8*rq + 4*lh;     // ascending within lane
        bool  lt = s < m1;
        m2 = fminf(m2, lt ? m1 : s);
        j1 = lt ? jj : j1;
        m1 = fminf(m1, s);
      }
    }
  }
  // merge halves; deterministic smaller-j tie-break (both halves converge)
  {
    float om1 = __shfl_xor(m1, 32);
    float om2 = __shfl_xor(m2, 32);
    int   oj1 = __shfl_xor(j1, 32);
    float nm2 = fminf(fminf(m2, om2), fmaxf(m1, om1));
    if (om1 < m1 || (om1 == m1 && oj1 < j1)){ m1 = om1; j1 = oj1; }
    m2 = nm2;
  }

  // near-tie enqueue: ref-fp32 quantization can flip only within 2*ulp(zz)
  {
    float zs = zz*1.02f + 0.1f;
    float ub = __builtin_bit_cast(float,
                 __builtin_bit_cast(unsigned, zs) & 0x7F800000u) * 1.1920929e-7f;
    float thr = 2.0f*ub + 1.0e-6f;
    if ((m2 - m1 <= thr) && lh == 0){
      unsigned slot = atomicAdd(&qn_lds, 1u);
      if (slot < segcap)
        qrows[(size_t)blockIdx.x*segcap + slot] = (unsigned)r | ((unsigned)j1 << 18);
    }
  }

  // full epilogue for EVERY row with coarse j1 (rescue patches diffs later)
  if (lh == 0){
    out[(size_t)OUT_IDX + r] = (float)j1;
    atomicAdd(&hist[j1], 1u);
  }
  double lsum = 0.0;
  {
    const float* Er = W + (size_t)(pos*NJ + j1)*64;
    float* zq = out + (size_t)b_i * 1048576 + t;
    #pragma unroll
    for (int ks = 0; ks < 4; ks++){
      const int d0 = ks*16 + lh*8;
      f32x4 ea = *(const f32x4*)(Er + d0);
      f32x4 eb = *(const f32x4*)(Er + d0 + 4);
      f32x4 za = *(const f32x4*)(zr + d0);
      f32x4 zb = *(const f32x4*)(zr + d0 + 4);
      #pragma unroll
      for (int i = 0; i < 8; i++){
        float e  = (i < 4) ? ea[i] : eb[i-4];
        float zv = (i < 4) ? za[i] : zb[i-4];
        float df = e - zv;
        lsum = fma((double)df, (double)df, lsum);
        zq[(size_t)(d0 + i) * 16384] = zv + df;
      }
    }
  }
  #pragma unroll
  for (int off = 1; off < 64; off <<= 1) lsum += __shfl_xor(lsum, off);
  if (l == 0) sLoss[w] = lsum;
  __syncthreads();

  if (tid == 0){
    double bs = 0.0;
    #pragma unroll
    for (int i = 0; i < 8; i++) bs += sLoss[i];
    lossA[blockIdx.x] = bs;
    qn[blockIdx.x] = min(qn_lds, segcap);
  }
  if (tid < NJ){
    unsigned c = hist[tid];
    if (c) atomicAdd(wsCnt4 + ((blockIdx.x & 3) * NJ) + tid, (int)c);
  }
}

// numpy-fp32 bit-exact replay for queued rows; PATCH only rows whose
// np-argmin differs from the coarse one.
__global__ __launch_bounds__(256, 2) void vq_rescue(
    const float* __restrict__ z, const float* __restrict__ oh,
    const float* __restrict__ W, float* __restrict__ out,
    double* __restrict__ lossB, int* __restrict__ wsCnt4,
    const unsigned* __restrict__ qn, const unsigned* __restrict__ qrows,
    unsigned segcap)
{
  #pragma clang fp contract(off)
  __shared__ float elds[NJ*64];   // exact fp32 E, element-XOR swizzled
  __shared__ float eeb[NJ];       // numpy-pairwise-8 ||e_j||^2 (bit-exact)

  float mvv = oh[0]; int pos = 0;
  #pragma unroll
  for (int i = 1; i < 7; i++){ float v = oh[i]; if (v > mvv){ mvv = v; pos = i; } }
  const float* E = W + (size_t)pos * (NJ*64);

  const int tid = threadIdx.x;
  {
    const float* er = E + (size_t)tid * 64;
    float p8[8];
    #pragma unroll
    for (int k = 0; k < 8; k++){
      float ev = er[k];
      elds[tid*64 + (k ^ (tid & 31))] = ev;
      p8[k] = ev*ev;
    }
    #pragma unroll
    for (int k = 8; k < 64; k++){
      float ev = er[k];
      elds[tid*64 + (k ^ (tid & 31))] = ev;
      p8[k & 7] += ev*ev;
    }
    eeb[tid] = ((p8[0]+p8[1])+(p8[2]+p8[3]))+((p8[4]+p8[5])+(p8[6]+p8[7]));
  }
  __syncthreads();

  const int wv = tid >> 6, l = tid & 63;
  const int x  = l & 31;
  const unsigned wgid = blockIdx.x*4u + (unsigned)wv;   // 0..2047
  const unsigned seg  = wgid >> 1;                       // 0..1023
  const unsigned sub  = wgid & 1u;
  const unsigned n    = min(qn[seg], segcap);

  double rloss = 0.0;

  for (unsigned i = sub; i < n; i += 2){
    const unsigned v = qrows[(size_t)seg*segcap + i];
    const int r    = __builtin_amdgcn_readfirstlane((int)(v & 0x3FFFFu));
    const int jold = __builtin_amdgcn_readfirstlane((int)((v >> 18) & 0xFFu));
    const float* zr = z + (size_t)r * 64;

    float zk[64];
    #pragma unroll
    for (int k = 0; k < 64; k++) zk[k] = zr[k];

    // numpy pairwise (8-acc) sum of fl(zk^2)
    float r8[8];
    #pragma unroll
    for (int k = 0; k < 8; k++){ float p = zk[k]*zk[k]; r8[k] = p; }
    #pragma unroll
    for (int k = 8; k < 64; k++){ float p = zk[k]*zk[k]; r8[k & 7] += p; }
    const float zzs = ((r8[0]+r8[1])+(r8[2]+r8[3]))+((r8[4]+r8[5])+(r8[6]+r8[7]));

    float dbest = 3.4e38f; int jbest = 0;
    #pragma unroll
    for (int q = 0; q < 4; q++){
      const int j = l + 64*q;
      float dot = 0.0f;
      #pragma unroll
      for (int k = 0; k < 64; k++){
        float ev = elds[j*64 + (k ^ x)];
        dot = fmaf(ev, zk[k], dot);
      }
      float A  = zzs + eeb[j];
      float tw = 2.0f*dot;
      float d  = A - tw;
      if (d < dbest){ dbest = d; jbest = j; }
    }
    #pragma unroll
    for (int off = 32; off > 0; off >>= 1){
      float od = __shfl_xor(dbest, off);
      int   oj = __shfl_xor(jbest, off);
      if (od < dbest || (od == dbest && oj < jbest)){ dbest = od; jbest = oj; }
    }

    if (jbest != jold){
      const int b_i = r >> 14;
      const int t   = r & 16383;
      const float* en_ = E + (size_t)jbest * 64;
      const float* eo_ = E + (size_t)jold  * 64;
      float ze  = zr[l];
      float dfn = en_[l] - ze;
      float dfo = eo_[l] - ze;
      out[(size_t)b_i * 1048576 + (size_t)l * 16384 + t] = ze + dfn;
      double dl = (double)dfn*(double)dfn - (double)dfo*(double)dfo;
      #pragma unroll
      for (int off = 1; off < 64; off <<= 1) dl += __shfl_xor(dl, off);
      rloss += dl;
      if (l == 0){
        out[(size_t)OUT_IDX + r] = (float)jbest;
        atomicAdd(wsCnt4 + jold,  -1);
        atomicAdd(wsCnt4 + jbest,  1);
      }
    }
  }
  if (l == 0) lossB[wgid] = rloss;
}

__global__ __launch_bounds__(1024) void vq_fin(
    const double* __restrict__ lossA, const double* __restrict__ lossB,
    const int* __restrict__ wsCnt4, float* __restrict__ out)
{
  __shared__ double sh[1024];
  __shared__ double sent[NJ];
  const int t = threadIdx.x;

  sh[t] = lossA[t] + lossB[t] + lossB[1024 + t];
  __syncthreads();
  for (int st = 512; st > 0; st >>= 1){
    if (t < st) sh[t] += sh[t + st];
    __syncthreads();
  }
  if (t < NJ){
    int c = wsCnt4[t] + wsCnt4[256+t] + wsCnt4[512+t] + wsCnt4[768+t];
    double em = (double)c / (double)NROWS;
    sent[t] = em * log(em + 1e-10);
  }
  __syncthreads();
  for (int st = 128; st > 0; st >>= 1){
    if (t < st) sent[t] += sent[t + st];
    __syncthreads();
  }
  if (t == 0){
    out[OUT_LOSS] = (float)(1.25 * (sh[0] / 16777216.0));
    out[OUT_PERP] = (float)exp(-sent[0]);
  }
}

extern "C" void kernel_launch(void* const* d_in, const int* in_sizes, int n_in,
                              void* d_out, int out_size, void* d_ws, size_t ws_size,
                              hipStream_t stream)
{
  const float* z  = (const float*)d_in[0];
  const float* oh = (const float*)d_in[1];
  const float* W  = (const float*)d_in[2];
  float* out = (float*)d_out;

  char* ws = (char*)d_ws;
  int*      wsCnt4 = (int*)(ws + 0);
  unsigned* qn     = (unsigned*)(ws + 4096);
  double*   lossA  = (double*)(ws + 8192);
  double*   lossB  = (double*)(ws + 16384);
  unsigned* qrows  = (unsigned*)(ws + 32768);

  unsigned segcap = 0;
  if (ws_size > 32768 + 4096){
    size_t cap = (ws_size - 32768) / (1024 * 4);
    segcap = (unsigned)(cap > 256 ? 256 : cap);
  }

  hipMemsetAsync(d_ws, 0, 4096, stream);
  vq_main<<<dim3(NBLK), dim3(512), 0, stream>>>(z, oh, W, out, lossA, wsCnt4,
                                                qn, qrows, segcap);
  vq_rescue<<<dim3(512), dim3(256), 0, stream>>>(z, oh, W, out, lossB, wsCnt4,
                                                 qn, qrows, segcap);
  vq_fin<<<dim3(1), dim3(1024), 0, stream>>>(lossA, lossB, wsCnt4, out);
}

// Round 5
// 176.205 us; speedup vs baseline: 2.7007x; 1.1609x over previous
//
#include <hip/hip_runtime.h>

#define NROWS (16*16384)   // 262144
#define NJ 256
#define OUT_LOSS 16777216
#define OUT_PERP 16777217
#define OUT_IDX  16777218

typedef float f32x4  __attribute__((ext_vector_type(4)));
typedef float f32x16 __attribute__((ext_vector_type(16)));
typedef short s16x8  __attribute__((ext_vector_type(8)));

// ws layout: [0,4096) wsCnt4[4][256] int (memset 0) | [4096,6144) lossA[256] f64

__global__ __launch_bounds__(512, 2) void vq_main(
    const float* __restrict__ z, const float* __restrict__ oh,
    const float* __restrict__ W, float* __restrict__ out,
    double* __restrict__ lossA, int* __restrict__ wsCnt4)
{
  #pragma clang fp contract(off)
  __shared__ short e1l[NJ*64];     // 32 KB bf16-hi, XOR slot swizzle
  __shared__ short e2l[NJ*64];     // 32 KB bf16-lo
  __shared__ float enl[NJ];
  __shared__ unsigned hist[NJ];
  __shared__ double sLoss[8];
  __shared__ int cand[8][32][8];   // per-wave per-row candidate list
  __shared__ unsigned ccnt[8][32];

  float mv = oh[0]; int pos = 0;
  #pragma unroll
  for (int i = 1; i < 7; i++){ float v = oh[i]; if (v > mv){ mv = v; pos = i; } }

  const int tid = threadIdx.x;          // 0..511
  const int w = tid >> 6, l = tid & 63, l31 = l & 31, lh = l >> 5;
  const int rbase = (int)blockIdx.x*1024 + w*32 + l31;   // +b*256

  // ---- batch-0 z prefetch: issue before staging, consume after barrier ----
  f32x4 zv[8];
  {
    const float* zr = z + (size_t)rbase * 64;
    #pragma unroll
    for (int ks = 0; ks < 4; ks++){
      zv[2*ks]   = *(const f32x4*)(zr + ks*16 + lh*8);
      zv[2*ks+1] = *(const f32x4*)(zr + ks*16 + lh*8 + 4);
    }
  }

  // ---- stage codebook: truncation split (exact residual), XOR slot swizzle ----
  {
    const int j = tid >> 1, half = tid & 1;
    const float* Wr = W + (size_t)(pos*NJ + j)*64;
    double en = 0.0;
    #pragma unroll
    for (int s4 = 0; s4 < 4; s4++){
      const int s = half*4 + s4;
      f32x4 a = *(const f32x4*)(Wr + s*8);
      f32x4 bq = *(const f32x4*)(Wr + s*8 + 4);
      s16x8 p1, p2;
      #pragma unroll
      for (int i = 0; i < 8; i++){
        float vv = (i < 4) ? a[i] : bq[i-4];
        unsigned ub = __builtin_bit_cast(unsigned, vv);
        float rr = vv - __builtin_bit_cast(float, ub & 0xFFFF0000u);  // exact
        p1[i] = (short)(unsigned short)(ub >> 16);
        p2[i] = (short)(unsigned short)(__builtin_bit_cast(unsigned, rr) >> 16);
        en += (double)vv * (double)vv;
      }
      const int slot = s ^ (j & 7);
      *(s16x8*)(e1l + j*64 + slot*8) = p1;
      *(s16x8*)(e2l + j*64 + slot*8) = p2;
    }
    en += __shfl_xor(en, 1);
    if (half == 0) enl[j] = (float)en;
    if (tid < NJ) hist[tid] = 0u;
  }
  __syncthreads();

  double lsum = 0.0;

  #pragma unroll 1
  for (int b = 0; b < 4; b++){
    const int r    = rbase + b*256;
    const int b_i  = r >> 14;
    const int t    = r & 16383;
    const float* zr = z + (size_t)r * 64;

    // ---- convert z (truncation split) ----
    float zzp = 0.0f;
    s16x8 z1f[4], z2f[4];
    #pragma unroll
    for (int ks = 0; ks < 4; ks++){
      #pragma unroll
      for (int i = 0; i < 8; i++){
        float vv = (i < 4) ? zv[2*ks][i] : zv[2*ks+1][i-4];
        zzp = fmaf(vv, vv, zzp);
        unsigned ub = __builtin_bit_cast(unsigned, vv);
        float rr = vv - __builtin_bit_cast(float, ub & 0xFFFF0000u);
        z1f[ks][i] = (short)(unsigned short)(ub >> 16);
        z2f[ks][i] = (short)(unsigned short)(__builtin_bit_cast(unsigned, rr) >> 16);
      }
    }
    const float zz = zzp + __shfl_xor(zzp, 32);

    // ---- split-precision MFMA: acc = dot(e_j, z_r) ----
    f32x16 acc[8] = {};
    #pragma unroll
    for (int ks = 0; ks < 4; ks++){
      #pragma unroll
      for (int jt = 0; jt < 8; jt++){
        const int jrow = jt*32 + l31;
        const int slot = (ks*2 + lh) ^ (jrow & 7);
        const s16x8 e1f = *(const s16x8*)(e1l + jrow*64 + slot*8);
        const s16x8 e2f = *(const s16x8*)(e2l + jrow*64 + slot*8);
        acc[jt] = __builtin_amdgcn_mfma_f32_32x32x16_bf16(e1f, z1f[ks], acc[jt], 0, 0, 0);
        acc[jt] = __builtin_amdgcn_mfma_f32_32x32x16_bf16(e1f, z2f[ks], acc[jt], 0, 0, 0);
        acc[jt] = __builtin_amdgcn_mfma_f32_32x32x16_bf16(e2f, z1f[ks], acc[jt], 0, 0, 0);
      }
    }

    // ---- lane-local (min, runner-up, argmin) ----
    float m1 = 3.4e38f, m2 = 3.4e38f; int j1 = 0;
    #pragma unroll
    for (int jt = 0; jt < 8; jt++){
      #pragma unroll
      for (int rq = 0; rq < 4; rq++){
        f32x4 en4 = *(const f32x4*)(enl + jt*32 + rq*8 + lh*4);
        #pragma unroll
        for (int q = 0; q < 4; q++){
          float s  = fmaf(-2.0f, acc[jt][rq*4+q], en4[q]);
          int   jj = jt*32 + q + 8*rq + 4*lh;
          bool  lt = s < m1;
          m2 = fminf(m2, lt ? m1 : s);
          j1 = lt ? jj : j1;
          m1 = fminf(m1, s);
        }
      }
    }
    {
      float om1 = __shfl_xor(m1, 32);
      float om2 = __shfl_xor(m2, 32);
      int   oj1 = __shfl_xor(j1, 32);
      float nm2 = fminf(fminf(m2, om2), fmaxf(m1, om1));
      if (om1 < m1 || (om1 == m1 && oj1 < j1)){ m1 = om1; j1 = oj1; }
      m2 = nm2;
    }

    // ---- flag + candidate collection (np-fp32 quantization zone) ----
    float zs = zz*1.02f + 0.1f;
    float ub = __builtin_bit_cast(float,
                 __builtin_bit_cast(unsigned, zs) & 0x7F800000u) * 1.1920929e-7f;
    const float thr = 2.0f*ub + 4.0e-6f;
    const bool flag = (m2 - m1 <= thr);
    if (lh == 0) ccnt[w][l31] = 0u;
    if (flag){
      #pragma unroll
      for (int jt = 0; jt < 8; jt++){
        #pragma unroll
        for (int rq = 0; rq < 4; rq++){
          f32x4 en4 = *(const f32x4*)(enl + jt*32 + rq*8 + lh*4);
          #pragma unroll
          for (int q = 0; q < 4; q++){
            float s = fmaf(-2.0f, acc[jt][rq*4+q], en4[q]);
            if (s <= m1 + thr){
              unsigned u = atomicAdd(&ccnt[w][l31], 1u);
              if (u < 8) cand[w][l31][u] = jt*32 + q + 8*rq + 4*lh;
            }
          }
        }
      }
    }

    // ---- prefetch next batch z (acc dead; hidden under replay+epilogue) ----
    if (b < 3){
      const float* zn = z + (size_t)(r + 256) * 64;
      #pragma unroll
      for (int ks = 0; ks < 4; ks++){
        zv[2*ks]   = *(const f32x4*)(zn + ks*16 + lh*8);
        zv[2*ks+1] = *(const f32x4*)(zn + ks*16 + lh*8 + 4);
      }
    }

    // ---- np-bit-exact replay of candidates, whole wave per flagged row ----
    unsigned rowmask = (unsigned)(__ballot(flag) & 0xFFFFFFFFull);
    while (rowmask){
      const int fr = __builtin_ctz(rowmask); rowmask &= rowmask - 1;
      const int rrow = (int)blockIdx.x*1024 + b*256 + w*32 + fr;   // uniform
      const float* zr2 = z + (size_t)rrow * 64;
      unsigned ncu = ccnt[w][fr]; int nc = (int)(ncu > 8u ? 8u : ncu);

      // numpy pairwise-8 sum of fl(z^2)  (uniform scalar loads)
      float r8[8];
      #pragma unroll
      for (int k = 0; k < 8; k++){ float p = zr2[k]*zr2[k]; r8[k] = p; }
      #pragma unroll
      for (int k = 8; k < 64; k++){ float p = zr2[k]*zr2[k]; r8[k & 7] += p; }
      const float zzs = ((r8[0]+r8[1])+(r8[2]+r8[3]))+((r8[4]+r8[5])+(r8[6]+r8[7]));

      float dbest = 3.4e38f; int jbest = 1 << 20;
      if (l < nc){
        const int jc = cand[w][fr][l];
        const float* er = W + (size_t)(pos*NJ + jc)*64;
        float dot = 0.0f; float s8[8];
        #pragma unroll
        for (int k = 0; k < 8; k++){
          float ev = er[k];
          dot = fmaf(ev, zr2[k], dot);
          s8[k] = ev*ev;
        }
        #pragma unroll
        for (int k = 8; k < 64; k++){
          float ev = er[k];
          dot = fmaf(ev, zr2[k], dot);
          s8[k & 7] += ev*ev;
        }
        float ee = ((s8[0]+s8[1])+(s8[2]+s8[3]))+((s8[4]+s8[5])+(s8[6]+s8[7]));
        float A  = zzs + ee;           // fp32 round (the np quantization)
        float tw = 2.0f*dot;           // exact
        dbest = A - tw;                // Sterbenz-exact subtraction
        jbest = jc;
      }
      #pragma unroll
      for (int off = 32; off > 0; off >>= 1){
        float od = __shfl_xor(dbest, off);
        int   oj = __shfl_xor(jbest, off);
        if (od < dbest || (od == dbest && oj < jbest)){ dbest = od; jbest = oj; }
      }
      if (l31 == fr) j1 = jbest;       // both halves of the owning pair
    }

    // ---- epilogue with FINAL j1: idx, hist, z_q (coalesced), loss ----
    if (lh == 0){
      out[(size_t)OUT_IDX + r] = (float)j1;
      atomicAdd(&hist[j1], 1u);
    }
    {
      const float* Er = W + (size_t)(pos*NJ + j1)*64;
      float* zq = out + (size_t)b_i * 1048576 + t;
      #pragma unroll
      for (int ks = 0; ks < 4; ks++){
        const int d0 = ks*16 + lh*8;
        f32x4 ea = *(const f32x4*)(Er + d0);
        f32x4 eb = *(const f32x4*)(Er + d0 + 4);
        f32x4 za = *(const f32x4*)(zr + d0);
        f32x4 zb = *(const f32x4*)(zr + d0 + 4);
        #pragma unroll
        for (int i = 0; i < 8; i++){
          float e  = (i < 4) ? ea[i] : eb[i-4];
          float zx = (i < 4) ? za[i] : zb[i-4];
          float df = e - zx;
          lsum = fma((double)df, (double)df, lsum);
          zq[(size_t)(d0 + i) * 16384] = zx + df;
        }
      }
    }
  }

  // ---- block loss + histogram flush (no contended global atomics) ----
  #pragma unroll
  for (int off = 1; off < 64; off <<= 1) lsum += __shfl_xor(lsum, off);
  if (l == 0) sLoss[w] = lsum;
  __syncthreads();
  if (tid == 0){
    double bs = 0.0;
    #pragma unroll
    for (int i = 0; i < 8; i++) bs += sLoss[i];
    lossA[blockIdx.x] = bs;
  }
  if (tid < NJ){
    unsigned c = hist[tid];
    if (c) atomicAdd(wsCnt4 + ((blockIdx.x & 3) * NJ) + tid, (int)c);
  }
}

__global__ void vq_fin(const double* __restrict__ lossA,
                       const int* __restrict__ wsCnt4,
                       float* __restrict__ out)
{
  __shared__ double sh[NJ];
  __shared__ double sent[NJ];
  const int t = threadIdx.x;
  sh[t] = lossA[t];
  int c = wsCnt4[t] + wsCnt4[256+t] + wsCnt4[512+t] + wsCnt4[768+t];
  double em = (double)c / (double)NROWS;
  sent[t] = em * log(em + 1e-10);
  __syncthreads();
  for (int s = 128; s > 0; s >>= 1){
    if (t < s){ sh[t] += sh[t + s]; sent[t] += sent[t + s]; }
    __syncthreads();
  }
  if (t == 0){
    out[OUT_LOSS] = (float)(1.25 * (sh[0] / 16777216.0));
    out[OUT_PERP] = (float)exp(-sent[0]);
  }
}

extern "C" void kernel_launch(void* const* d_in, const int* in_sizes, int n_in,
                              void* d_out, int out_size, void* d_ws, size_t ws_size,
                              hipStream_t stream)
{
  const float* z  = (const float*)d_in[0];
  const float* oh = (const float*)d_in[1];
  const float* W  = (const float*)d_in[2];
  float* out = (float*)d_out;

  char* ws = (char*)d_ws;
  int*    wsCnt4 = (int*)(ws + 0);
  double* lossA  = (double*)(ws + 4096);

  hipMemsetAsync(d_ws, 0, 4096, stream);
  vq_main<<<dim3(256), dim3(512), 0, stream>>>(z, oh, W, out, lossA, wsCnt4);
  vq_fin<<<dim3(1), dim3(256), 0, stream>>>(lossA, wsCnt4, out);
}